// Round 7
// baseline (287.916 us; speedup 1.0000x reference)
//
#include <hip/hip_runtime.h>
#include <stdint.h>

#define C_IN 256
#define C_MID 64
#define KOFF 9

typedef __attribute__((ext_vector_type(8))) short bf16x8;   // 8 bf16 = 4 VGPRs
typedef __attribute__((ext_vector_type(4))) short short4v;  // 8 B packed bf16x4
typedef __attribute__((ext_vector_type(4))) float f32x4;    // MFMA C/D
typedef __attribute__((ext_vector_type(4))) float float4v;

// fp32 -> bf16 round-to-nearest-even
__device__ inline unsigned short f2bf(float f) {
    union { float f; unsigned u; } x; x.f = f;
    unsigned r = x.u + 0x7FFFu + ((x.u >> 16) & 1u);
    return (unsigned short)(r >> 16);
}

// ---------------------------------------------------------------------------
// prep (unchanged):
//   w1t[n][k] = bf16(w1[k][n] * s1[n])          [64][256]   16384 shorts
//   w2t[k][d][c] = bf16(w2[k][c][d] * s2[d])    [9][64][64] 36864 shorts
//   w3t[e][c] = bf16(w3[c][e] * s3[e])          [256][64]   16384 shorts
// ---------------------------------------------------------------------------
__global__ void prep_kernel(const float* __restrict__ w1, const float* __restrict__ s1,
                            const float* __restrict__ w2, const float* __restrict__ s2,
                            const float* __restrict__ w3, const float* __restrict__ s3,
                            unsigned short* __restrict__ w1t,
                            unsigned short* __restrict__ w2t,
                            unsigned short* __restrict__ w3t,
                            unsigned short* __restrict__ zrow) {
    int tid = blockIdx.x * blockDim.x + threadIdx.x;
    int stride = gridDim.x * blockDim.x;
    for (int i = tid; i < C_MID * C_IN; i += stride) {
        int n = i / C_IN, k = i % C_IN;
        w1t[i] = f2bf(w1[k * C_MID + n] * s1[n]);
    }
    for (int i = tid; i < KOFF * C_MID * C_MID; i += stride) {
        int k = i / (C_MID * C_MID);
        int r = i % (C_MID * C_MID);
        int d = r / C_MID, c = r % C_MID;
        w2t[i] = f2bf(w2[(k * C_MID + c) * C_MID + d] * s2[d]);
    }
    for (int i = tid; i < C_IN * C_MID; i += stride) {
        int e = i / C_MID, c = i % C_MID;
        w3t[i] = f2bf(w3[c * C_IN + e] * s3[e]);
    }
    for (int i = tid; i < C_MID; i += stride) zrow[i] = 0;
}

// ---------------------------------------------------------------------------
// conv1 (unchanged from R6): role-swapped, weights=A from LDS, feat=B pinned.
// ---------------------------------------------------------------------------
__global__ __launch_bounds__(256, 4) void conv1_kernel(
    const float* __restrict__ feat, const unsigned short* __restrict__ w1t,
    const float* __restrict__ b1, unsigned short* __restrict__ out1, int N)
{
    __shared__ __align__(16) unsigned short sW1[16384];      // 32768 B

    int t = threadIdx.x;
    int wave = t >> 6;
    int lane = t & 63;
    int l15 = lane & 15;
    int quad = lane >> 4;
    int row_tile = blockIdx.x * 64;
    int site = row_tile + wave * 16 + l15;
    int sitec = site < N ? site : (N - 1);

    const bf16x8* w1c = reinterpret_cast<const bf16x8*>(w1t);
    bf16x8* sW1c = reinterpret_cast<bf16x8*>(sW1);
#pragma unroll
    for (int it = 0; it < 8; ++it) {
        int s = it * 256 + t;
        int l = s & 15, ct = (s >> 4) & 3, q = (s >> 6) & 3, kk = s >> 8;
        sW1c[s] = w1c[(ct * 16 + l) * 32 + kk * 4 + q];
    }

    float4v fr[16];
#pragma unroll
    for (int kk = 0; kk < 8; ++kk) {
        const float4v* p = reinterpret_cast<const float4v*>(
            feat + (size_t)sitec * C_IN + kk * 32 + quad * 8);
        fr[kk * 2] = p[0];
        fr[kk * 2 + 1] = p[1];
    }
    __builtin_amdgcn_sched_barrier(0);
    __syncthreads();

    f32x4 acc[4] = {};
#pragma unroll
    for (int kk = 0; kk < 8; ++kk) {
        union { unsigned short s[8]; bf16x8 v; } ua;
#pragma unroll
        for (int j = 0; j < 4; ++j) {
            ua.s[j] = f2bf(fr[kk * 2][j]);
            ua.s[4 + j] = f2bf(fr[kk * 2 + 1][j]);
        }
#pragma unroll
        for (int ct = 0; ct < 4; ++ct) {
            bf16x8 fa = sW1c[((kk * 4 + quad) * 4 + ct) * 16 + l15];
            acc[ct] = __builtin_amdgcn_mfma_f32_16x16x32_bf16(fa, ua.v, acc[ct], 0, 0, 0);
        }
    }
    if (site < N) {
#pragma unroll
        for (int ct = 0; ct < 4; ++ct) {
            const float4v* bp = reinterpret_cast<const float4v*>(b1 + ct * 16 + quad * 4);
            float4v bb = bp[0];
            union { unsigned short s[4]; short4v v; } o;
#pragma unroll
            for (int reg = 0; reg < 4; ++reg)
                o.s[reg] = f2bf(fmaxf(acc[ct][reg] + bb[reg], 0.f));
            *reinterpret_cast<short4v*>(out1 + (size_t)site * C_MID + ct * 16 + quad * 4) = o.v;
        }
    }
}

// ---------------------------------------------------------------------------
// conv2+conv3 v3: 512 threads, 2 site-tiles/block sharing one w2 LDS copy.
// LDS 78336 B -> 2 blocks/CU (16 waves). Register diet targets <=128 unified
// (4 waves/SIMD): conv3 + epilogue split into two 8-channel halves
// (acc3h=32 regs, rf/b3 pinned 32+32 per half), all pinned loads issued one
// phase ahead of use. mid pitch 72 (R5's 50K-conflict layout).
// ---------------------------------------------------------------------------
__global__ __launch_bounds__(512, 4) void conv23_kernel(
    const float* __restrict__ feat, const int* __restrict__ nbr,
    const unsigned short* __restrict__ out1, const unsigned short* __restrict__ w2t,
    const float* __restrict__ b2, const unsigned short* __restrict__ w3t,
    const float* __restrict__ b3, float* __restrict__ out, int N)
{
    __shared__ __align__(16) unsigned short sWB[36864];      // 73728 B
    __shared__ int sNbr[128 * KOFF];                         // 4608 B

    int t = threadIdx.x;
    int wave = t >> 6;                 // 0..7; waves 0-3 tile 0, 4-7 tile 1
    int lane = t & 63;
    int l15 = lane & 15;
    int quad = lane >> 4;
    int rt = wave * 16 + l15;          // site index within the 128-site block
    int site = blockIdx.x * 128 + rt;
    int sitec = site < N ? site : (N - 1);

    bf16x8* sWBc = reinterpret_cast<bf16x8*>(sWB);

    // ---- stage all of w2t: 4608 chunks / 512 thr = 9 each ----
    const bf16x8* w2c = reinterpret_cast<const bf16x8*>(w2t);
#pragma unroll
    for (int it = 0; it < 9; ++it) {
        int s = it * 512 + t;
        int l = s & 15, ct = (s >> 4) & 3, q = (s >> 6) & 3, kk = (s >> 8) & 1, k = s >> 9;
        sWBc[s] = w2c[k * 512 + (ct * 16 + l) * 8 + kk * 4 + q];
    }
    // ---- stage rulebook slice: 1152 ints ----
#pragma unroll
    for (int i = 0; i < 3; ++i) {
        int j = i * 512 + t;
        if (j < 128 * KOFF) {
            int g = blockIdx.x * 128 * KOFF + j;
            sNbr[j] = (g < N * KOFF) ? nbr[g] : N;
        }
    }
    __syncthreads();

    int nb[KOFF];
#pragma unroll
    for (int k = 0; k < KOFF; ++k) nb[k] = sNbr[rt * KOFF + k];

    // ---- pin 18 gathers (B-fragments) ----
    bf16x8 ga[KOFF][2];
#pragma unroll
    for (int k = 0; k < KOFF; ++k) {
        const bf16x8* pg = reinterpret_cast<const bf16x8*>(out1 + (size_t)nb[k] * C_MID + quad * 8);
        ga[k][0] = pg[0];
        ga[k][1] = pg[4];
    }
    __builtin_amdgcn_sched_barrier(0);

    f32x4 acc2[4] = {};
#pragma unroll
    for (int k = 0; k < KOFF; ++k) {
#pragma unroll
        for (int kk = 0; kk < 2; ++kk) {
#pragma unroll
            for (int ct = 0; ct < 4; ++ct) {
                bf16x8 fa = sWBc[((k * 2 + kk) * 4 + quad) * 64 + ct * 16 + l15]; // A: w2
                acc2[ct] = __builtin_amdgcn_mfma_f32_16x16x32_bf16(fa, ga[k][kk], acc2[ct], 0, 0, 0);
            }
        }
    }
    // ga dead. Issue phase-B consumables now: b2, rf half A, b3 half A.
    // They drain for free at the next barrier.
    float4v b2r[4];
#pragma unroll
    for (int ct = 0; ct < 4; ++ct)
        b2r[ct] = *reinterpret_cast<const float4v*>(b2 + ct * 16 + quad * 4);
    float4v rfA[8], b3A[8];
#pragma unroll
    for (int c8 = 0; c8 < 8; ++c8) {
        rfA[c8] = *reinterpret_cast<const float4v*>(
            feat + (size_t)sitec * C_IN + c8 * 16 + quad * 4);
        b3A[c8] = *reinterpret_cast<const float4v*>(b3 + c8 * 16 + quad * 4);
    }
    __builtin_amdgcn_sched_barrier(0);
    __syncthreads();   // all waves done reading w2 before overlay

    // ---- phase B overlay: w3 -> chunks 0..2047; mid (pitch 72) at shorts
    //      16384 + rt*72 (both tiles, 16384..25599, disjoint from w3) ----
    unsigned short* mid = &sWB[16384];
#pragma unroll
    for (int ct = 0; ct < 4; ++ct) {
        union { unsigned short s[4]; short4v v; } o;
#pragma unroll
        for (int reg = 0; reg < 4; ++reg)
            o.s[reg] = f2bf(fmaxf(acc2[ct][reg] + b2r[ct][reg], 0.f));
        *reinterpret_cast<short4v*>(&mid[rt * 72 + ct * 16 + quad * 4]) = o.v;
    }
    const bf16x8* w3c = reinterpret_cast<const bf16x8*>(w3t);
#pragma unroll
    for (int it = 0; it < 4; ++it) {
        int s = it * 512 + t;
        int l = s & 15, c2 = (s >> 4) & 15, q = (s >> 8) & 3, kk = (s >> 10) & 1;
        sWBc[s] = w3c[(c2 * 16 + l) * 8 + kk * 4 + q];
    }
    __syncthreads();   // mid + w3 visible (cross-lane LDS RAW — R3 lesson)

    // ---- issue half-B consumables (in flight during half-A compute) ----
    float4v rfB[8], b3B[8];
#pragma unroll
    for (int c8 = 0; c8 < 8; ++c8) {
        rfB[c8] = *reinterpret_cast<const float4v*>(
            feat + (size_t)sitec * C_IN + (8 + c8) * 16 + quad * 4);
        b3B[c8] = *reinterpret_cast<const float4v*>(b3 + (8 + c8) * 16 + quad * 4);
    }
    __builtin_amdgcn_sched_barrier(0);

    // ---- conv3 + epilogue in two 8-channel halves (acc3h = 32 regs) ----
#pragma unroll
    for (int half = 0; half < 2; ++half) {
        f32x4 acc3[8] = {};
#pragma unroll
        for (int kk = 0; kk < 2; ++kk) {
            bf16x8 fb = *reinterpret_cast<const bf16x8*>(
                &mid[rt * 72 + kk * 32 + quad * 8]);          // B: own site's mid row
#pragma unroll
            for (int c8 = 0; c8 < 8; ++c8) {
                int c2 = half * 8 + c8;
                bf16x8 fa = sWBc[((kk * 4 + quad) * 16 + c2) * 16 + l15];  // A: w3
                acc3[c8] = __builtin_amdgcn_mfma_f32_16x16x32_bf16(fa, fb, acc3[c8], 0, 0, 0);
            }
        }
        if (site < N) {
#pragma unroll
            for (int c8 = 0; c8 < 8; ++c8) {
                int c2 = half * 8 + c8;
                float4v bb = half ? b3B[c8] : b3A[c8];
                float4v rr = half ? rfB[c8] : rfA[c8];
                float4v o;
#pragma unroll
                for (int reg = 0; reg < 4; ++reg)
                    o[reg] = fmaxf(acc3[c8][reg] + bb[reg] + rr[reg], 0.f);
                *reinterpret_cast<float4v*>(out + (size_t)site * C_IN + c2 * 16 + quad * 4) = o;
            }
        }
    }
}

extern "C" void kernel_launch(void* const* d_in, const int* in_sizes, int n_in,
                              void* d_out, int out_size, void* d_ws, size_t ws_size,
                              hipStream_t stream) {
    const float* feat = (const float*)d_in[0];
    const int*   nbr  = (const int*)d_in[1];
    const float* w1   = (const float*)d_in[2];
    const float* s1   = (const float*)d_in[3];
    const float* b1   = (const float*)d_in[4];
    const float* w2   = (const float*)d_in[5];
    const float* s2   = (const float*)d_in[6];
    const float* b2   = (const float*)d_in[7];
    const float* w3   = (const float*)d_in[8];
    const float* s3   = (const float*)d_in[9];
    const float* b3   = (const float*)d_in[10];
    float* out = (float*)d_out;
    int N = in_sizes[0] / C_IN;

    char* ws = (char*)d_ws;
    unsigned short* w1t  = (unsigned short*)(ws);                    // 32768 B
    unsigned short* w2t  = (unsigned short*)(ws + 32768);            // 73728 B
    unsigned short* w3t  = (unsigned short*)(ws + 32768 + 73728);    // 32768 B
    unsigned short* out1 = (unsigned short*)(ws + 139264);           // (N+1)*64*2 B

    prep_kernel<<<80, 256, 0, stream>>>(w1, s1, w2, s2, w3, s3, w1t, w2t, w3t,
                                        out1 + (size_t)N * C_MID);
    conv1_kernel<<<(N + 63) / 64, 256, 0, stream>>>(feat, w1t, b1, out1, N);
    conv23_kernel<<<(N + 127) / 128, 512, 0, stream>>>(feat, nbr, out1, w2t, b2, w3t, b3, out, N);
}

// Round 8
// 261.639 us; speedup vs baseline: 1.1004x; 1.1004x over previous
//
#include <hip/hip_runtime.h>
#include <stdint.h>

#define C_IN 256
#define C_MID 64
#define KOFF 9

typedef __attribute__((ext_vector_type(8))) short bf16x8;   // 8 bf16 = 4 VGPRs
typedef __attribute__((ext_vector_type(4))) short short4v;  // 8 B packed bf16x4
typedef __attribute__((ext_vector_type(4))) float f32x4;    // MFMA C/D
typedef __attribute__((ext_vector_type(4))) float float4v;

// fp32 -> bf16 round-to-nearest-even
__device__ inline unsigned short f2bf(float f) {
    union { float f; unsigned u; } x; x.f = f;
    unsigned r = x.u + 0x7FFFu + ((x.u >> 16) & 1u);
    return (unsigned short)(r >> 16);
}

// ---------------------------------------------------------------------------
// prep (unchanged):
//   w1t[n][k] = bf16(w1[k][n] * s1[n])          [64][256]   16384 shorts
//   w2t[k][d][c] = bf16(w2[k][c][d] * s2[d])    [9][64][64] 36864 shorts
//   w3t[e][c] = bf16(w3[c][e] * s3[e])          [256][64]   16384 shorts
// ---------------------------------------------------------------------------
__global__ void prep_kernel(const float* __restrict__ w1, const float* __restrict__ s1,
                            const float* __restrict__ w2, const float* __restrict__ s2,
                            const float* __restrict__ w3, const float* __restrict__ s3,
                            unsigned short* __restrict__ w1t,
                            unsigned short* __restrict__ w2t,
                            unsigned short* __restrict__ w3t,
                            unsigned short* __restrict__ zrow) {
    int tid = blockIdx.x * blockDim.x + threadIdx.x;
    int stride = gridDim.x * blockDim.x;
    for (int i = tid; i < C_MID * C_IN; i += stride) {
        int n = i / C_IN, k = i % C_IN;
        w1t[i] = f2bf(w1[k * C_MID + n] * s1[n]);
    }
    for (int i = tid; i < KOFF * C_MID * C_MID; i += stride) {
        int k = i / (C_MID * C_MID);
        int r = i % (C_MID * C_MID);
        int d = r / C_MID, c = r % C_MID;
        w2t[i] = f2bf(w2[(k * C_MID + c) * C_MID + d] * s2[d]);
    }
    for (int i = tid; i < C_IN * C_MID; i += stride) {
        int e = i / C_MID, c = i % C_MID;
        w3t[i] = f2bf(w3[c * C_IN + e] * s3[e]);
    }
    for (int i = tid; i < C_MID; i += stride) zrow[i] = 0;
}

// ---------------------------------------------------------------------------
// conv1 v4: role-swapped, LDS = sW1 only (32.8 KB -> 4 blocks/CU). fr loads
// split into two pinned groups of 8 float4 (peak ~95 regs <= 128 cap, no
// spill). Group 1 is in flight while group 0 feeds MFMAs.
// ---------------------------------------------------------------------------
__global__ __launch_bounds__(256, 4) void conv1_kernel(
    const float* __restrict__ feat, const unsigned short* __restrict__ w1t,
    const float* __restrict__ b1, unsigned short* __restrict__ out1, int N)
{
    __shared__ __align__(16) unsigned short sW1[16384];      // 32768 B

    int t = threadIdx.x;
    int wave = t >> 6;
    int lane = t & 63;
    int l15 = lane & 15;
    int quad = lane >> 4;
    int site = blockIdx.x * 64 + wave * 16 + l15;
    int sitec = site < N ? site : (N - 1);

    const bf16x8* w1c = reinterpret_cast<const bf16x8*>(w1t);
    bf16x8* sW1c = reinterpret_cast<bf16x8*>(sW1);
#pragma unroll
    for (int it = 0; it < 8; ++it) {
        int s = it * 256 + t;
        int l = s & 15, ct = (s >> 4) & 3, q = (s >> 6) & 3, kk = s >> 8;
        sW1c[s] = w1c[(ct * 16 + l) * 32 + kk * 4 + q];
    }

    // ---- pin group 0: kk = 0..3 (8 float4 = 32 regs) ----
    float4v fr0[8];
#pragma unroll
    for (int kk = 0; kk < 4; ++kk) {
        const float4v* p = reinterpret_cast<const float4v*>(
            feat + (size_t)sitec * C_IN + kk * 32 + quad * 8);
        fr0[kk * 2] = p[0];
        fr0[kk * 2 + 1] = p[1];
    }
    __builtin_amdgcn_sched_barrier(0);
    __syncthreads();

    // ---- pin group 1: kk = 4..7 (in flight during group-0 compute) ----
    float4v fr1[8];
#pragma unroll
    for (int kk = 0; kk < 4; ++kk) {
        const float4v* p = reinterpret_cast<const float4v*>(
            feat + (size_t)sitec * C_IN + (kk + 4) * 32 + quad * 8);
        fr1[kk * 2] = p[0];
        fr1[kk * 2 + 1] = p[1];
    }
    __builtin_amdgcn_sched_barrier(0);

    f32x4 acc[4] = {};
#pragma unroll
    for (int kk = 0; kk < 4; ++kk) {
        union { unsigned short s[8]; bf16x8 v; } ua;
#pragma unroll
        for (int j = 0; j < 4; ++j) {
            ua.s[j] = f2bf(fr0[kk * 2][j]);
            ua.s[4 + j] = f2bf(fr0[kk * 2 + 1][j]);
        }
#pragma unroll
        for (int ct = 0; ct < 4; ++ct) {
            bf16x8 fa = sW1c[((kk * 4 + quad) * 4 + ct) * 16 + l15];
            acc[ct] = __builtin_amdgcn_mfma_f32_16x16x32_bf16(fa, ua.v, acc[ct], 0, 0, 0);
        }
    }
#pragma unroll
    for (int kk = 0; kk < 4; ++kk) {
        union { unsigned short s[8]; bf16x8 v; } ua;
#pragma unroll
        for (int j = 0; j < 4; ++j) {
            ua.s[j] = f2bf(fr1[kk * 2][j]);
            ua.s[4 + j] = f2bf(fr1[kk * 2 + 1][j]);
        }
#pragma unroll
        for (int ct = 0; ct < 4; ++ct) {
            bf16x8 fa = sW1c[(((kk + 4) * 4 + quad) * 4 + ct) * 16 + l15];
            acc[ct] = __builtin_amdgcn_mfma_f32_16x16x32_bf16(fa, ua.v, acc[ct], 0, 0, 0);
        }
    }
    if (site < N) {
#pragma unroll
        for (int ct = 0; ct < 4; ++ct) {
            float4v bb = *reinterpret_cast<const float4v*>(b1 + ct * 16 + quad * 4);
            union { unsigned short s[4]; short4v v; } o;
#pragma unroll
            for (int reg = 0; reg < 4; ++reg)
                o.s[reg] = f2bf(fmaxf(acc[ct][reg] + bb[reg], 0.f));
            *reinterpret_cast<short4v*>(out1 + (size_t)site * C_MID + ct * 16 + quad * 4) = o.v;
        }
    }
}

// ---------------------------------------------------------------------------
// conv2+conv3 v4 (R6 structure, occupancy fix): w2 LDS residency split into
// two phases (k=0..4 then k=5..8 overlaid) -> LDS 45312 B -> 3 blocks/CU.
// rf pin moved AFTER conv2 (ga dead) -> peak live ~150 regs <= 170
// (3 waves/SIMD at 512-reg/SIMD pool). Buffer layout:
//   A1: w2 k0-4 chunks 0..2559 | A2: w2 k5-8 chunks 0..2047
//   B : w3 chunks 0..2047 | mid shorts 16384..20991 (pitch 72)
// ---------------------------------------------------------------------------
__global__ __launch_bounds__(256, 2) void conv23_kernel(
    const float* __restrict__ feat, const int* __restrict__ nbr,
    const unsigned short* __restrict__ out1, const unsigned short* __restrict__ w2t,
    const float* __restrict__ b2, const unsigned short* __restrict__ w3t,
    const float* __restrict__ b3, float* __restrict__ out, int N)
{
    __shared__ __align__(16) unsigned short sWB[21504];      // 43008 B
    __shared__ int sNbr[64 * KOFF];                          // 2304 B

    int t = threadIdx.x;
    int wave = t >> 6;
    int lane = t & 63;
    int l15 = lane & 15;
    int quad = lane >> 4;
    int rt = wave * 16 + l15;
    int site = blockIdx.x * 64 + rt;
    int sitec = site < N ? site : (N - 1);

    bf16x8* sWBc = reinterpret_cast<bf16x8*>(sWB);
    const bf16x8* w2c = reinterpret_cast<const bf16x8*>(w2t);

    // ---- A1 stage: w2 k=0..4, 2560 chunks / 256 thr = 10 each ----
#pragma unroll
    for (int it = 0; it < 10; ++it) {
        int s = it * 256 + t;
        int l = s & 15, ct = (s >> 4) & 3, q = (s >> 6) & 3, kk = (s >> 8) & 1, k = s >> 9;
        sWBc[s] = w2c[k * 512 + (ct * 16 + l) * 8 + kk * 4 + q];
    }
#pragma unroll
    for (int i = 0; i < 3; ++i) {
        int j = i * 256 + t;
        if (j < 64 * KOFF) {
            int g = blockIdx.x * 64 * KOFF + j;
            sNbr[j] = (g < N * KOFF) ? nbr[g] : N;
        }
    }
    __syncthreads();                                         // B1

    int nb[KOFF];
#pragma unroll
    for (int k = 0; k < KOFF; ++k) nb[k] = sNbr[rt * KOFF + k];

    // ---- pin 18 gathers ----
    bf16x8 ga[KOFF][2];
#pragma unroll
    for (int k = 0; k < KOFF; ++k) {
        const bf16x8* pg = reinterpret_cast<const bf16x8*>(out1 + (size_t)nb[k] * C_MID + quad * 8);
        ga[k][0] = pg[0];
        ga[k][1] = pg[4];
    }
    __builtin_amdgcn_sched_barrier(0);

    f32x4 acc2[4] = {};
#pragma unroll
    for (int k = 0; k < 5; ++k) {
#pragma unroll
        for (int kk = 0; kk < 2; ++kk) {
#pragma unroll
            for (int ct = 0; ct < 4; ++ct) {
                bf16x8 fa = sWBc[((k * 2 + kk) * 4 + quad) * 64 + ct * 16 + l15];
                acc2[ct] = __builtin_amdgcn_mfma_f32_16x16x32_bf16(fa, ga[k][kk], acc2[ct], 0, 0, 0);
            }
        }
    }
    __syncthreads();                                         // B2: w2 part1 read done

    // ---- A2 stage: w2 k=5..8 overlaid into chunks 0..2047 ----
#pragma unroll
    for (int it = 0; it < 8; ++it) {
        int s = it * 256 + t;
        int l = s & 15, ct = (s >> 4) & 3, q = (s >> 6) & 3, kk = (s >> 8) & 1, k2 = s >> 9;
        sWBc[s] = w2c[(5 + k2) * 512 + (ct * 16 + l) * 8 + kk * 4 + q];
    }
    __syncthreads();                                         // B3
#pragma unroll
    for (int k = 5; k < KOFF; ++k) {
        int kloc = k - 5;
#pragma unroll
        for (int kk = 0; kk < 2; ++kk) {
#pragma unroll
            for (int ct = 0; ct < 4; ++ct) {
                bf16x8 fa = sWBc[((kloc * 2 + kk) * 4 + quad) * 64 + ct * 16 + l15];
                acc2[ct] = __builtin_amdgcn_mfma_f32_16x16x32_bf16(fa, ga[k][kk], acc2[ct], 0, 0, 0);
            }
        }
    }
    // ga dead — pin rf now (drains during staging + barrier)
    float4v rf[16];
#pragma unroll
    for (int c2 = 0; c2 < 16; ++c2)
        rf[c2] = *reinterpret_cast<const float4v*>(
            feat + (size_t)sitec * C_IN + c2 * 16 + quad * 4);
    __builtin_amdgcn_sched_barrier(0);
    __syncthreads();                                         // B4: w2 part2 read done

    // ---- phase B: mid (pitch 72) at shorts 16384..20991; w3 chunks 0..2047 ----
    unsigned short* mid = &sWB[16384];
#pragma unroll
    for (int ct = 0; ct < 4; ++ct) {
        float4v bb = *reinterpret_cast<const float4v*>(b2 + ct * 16 + quad * 4);
        union { unsigned short s[4]; short4v v; } o;
#pragma unroll
        for (int reg = 0; reg < 4; ++reg)
            o.s[reg] = f2bf(fmaxf(acc2[ct][reg] + bb[reg], 0.f));
        *reinterpret_cast<short4v*>(&mid[rt * 72 + ct * 16 + quad * 4]) = o.v;
    }
    const bf16x8* w3c = reinterpret_cast<const bf16x8*>(w3t);
#pragma unroll
    for (int it = 0; it < 8; ++it) {
        int s = it * 256 + t;
        int l = s & 15, c2 = (s >> 4) & 15, q = (s >> 8) & 3, kk = (s >> 10) & 1;
        sWBc[s] = w3c[(c2 * 16 + l) * 8 + kk * 4 + q];
    }
    __syncthreads();                                         // B5 (cross-lane LDS RAW)

    f32x4 acc3[16] = {};
#pragma unroll
    for (int kk = 0; kk < 2; ++kk) {
        bf16x8 fb = *reinterpret_cast<const bf16x8*>(
            &mid[rt * 72 + kk * 32 + quad * 8]);
#pragma unroll
        for (int c2 = 0; c2 < 16; ++c2) {
            bf16x8 fa = sWBc[((kk * 4 + quad) * 16 + c2) * 16 + l15];
            acc3[c2] = __builtin_amdgcn_mfma_f32_16x16x32_bf16(fa, fb, acc3[c2], 0, 0, 0);
        }
    }
    if (site < N) {
#pragma unroll
        for (int c2 = 0; c2 < 16; ++c2) {
            float4v bb = *reinterpret_cast<const float4v*>(b3 + c2 * 16 + quad * 4);
            float4v o;
#pragma unroll
            for (int reg = 0; reg < 4; ++reg)
                o[reg] = fmaxf(acc3[c2][reg] + bb[reg] + rf[c2][reg], 0.f);
            *reinterpret_cast<float4v*>(out + (size_t)site * C_IN + c2 * 16 + quad * 4) = o;
        }
    }
}

extern "C" void kernel_launch(void* const* d_in, const int* in_sizes, int n_in,
                              void* d_out, int out_size, void* d_ws, size_t ws_size,
                              hipStream_t stream) {
    const float* feat = (const float*)d_in[0];
    const int*   nbr  = (const int*)d_in[1];
    const float* w1   = (const float*)d_in[2];
    const float* s1   = (const float*)d_in[3];
    const float* b1   = (const float*)d_in[4];
    const float* w2   = (const float*)d_in[5];
    const float* s2   = (const float*)d_in[6];
    const float* b2   = (const float*)d_in[7];
    const float* w3   = (const float*)d_in[8];
    const float* s3   = (const float*)d_in[9];
    const float* b3   = (const float*)d_in[10];
    float* out = (float*)d_out;
    int N = in_sizes[0] / C_IN;

    char* ws = (char*)d_ws;
    unsigned short* w1t  = (unsigned short*)(ws);                    // 32768 B
    unsigned short* w2t  = (unsigned short*)(ws + 32768);            // 73728 B
    unsigned short* w3t  = (unsigned short*)(ws + 32768 + 73728);    // 32768 B
    unsigned short* out1 = (unsigned short*)(ws + 139264);           // (N+1)*64*2 B

    prep_kernel<<<80, 256, 0, stream>>>(w1, s1, w2, s2, w3, s3, w1t, w2t, w3t,
                                        out1 + (size_t)N * C_MID);
    int nblk = (N + 63) / 64;
    conv1_kernel<<<nblk, 256, 0, stream>>>(feat, w1t, b1, out1, N);
    conv23_kernel<<<nblk, 256, 0, stream>>>(feat, nbr, out1, w2t, b2, w3t, b3, out, N);
}